// Round 3
// baseline (2514.863 us; speedup 1.0000x reference)
//
#include <hip/hip_runtime.h>
#include <hip/hip_bf16.h>
#include <stdint.h>

#define N_USER 100000
#define N_ITEM 50000
#define NTOT   150000
#define NEDGE  1200000
#define D      64
#define OUTD   256
#define NEG    0.01f
#define NBLK   586   // ceil(150000/256)

// Build E = concat(user_emb, item_emb) and write output chunk 0 (raw emb, fp32)
__global__ void k_init(const float* __restrict__ ue, const float* __restrict__ ie,
                       float* __restrict__ E, float* __restrict__ out) {
    int t = blockIdx.x * blockDim.x + threadIdx.x;
    if (t >= NTOT * 16) return;
    int r = t >> 4, q = t & 15;
    const float* src = (r < N_USER) ? (ue + (size_t)r * D)
                                    : (ie + (size_t)(r - N_USER) * D);
    float4 v = *(const float4*)(src + q * 4);
    *(float4*)(E + (size_t)r * D + q * 4) = v;
    *(float4*)(out + (size_t)r * OUTD + q * 4) = v;
}

__global__ void k_hist(const int* __restrict__ row, int* __restrict__ cnt) {
    int e = blockIdx.x * blockDim.x + threadIdx.x;
    if (e < NEDGE) atomicAdd(&cnt[row[e]], 1);
}

// Phase A: per-block (256) partial sums of counts
__global__ void k_scan_a(const int* __restrict__ cnt, int* __restrict__ part) {
    __shared__ int s[4];
    int i = blockIdx.x * 256 + threadIdx.x;
    int v = (i < NTOT) ? cnt[i] : 0;
    for (int off = 32; off; off >>= 1) v += __shfl_down(v, off, 64);
    if ((threadIdx.x & 63) == 0) s[threadIdx.x >> 6] = v;
    __syncthreads();
    if (threadIdx.x == 0) part[blockIdx.x] = s[0] + s[1] + s[2] + s[3];
}

// Phase B: single-block exclusive scan of NBLK partials
__global__ void k_scan_b(int* __restrict__ part) {
    __shared__ int s[1024];
    int t = threadIdx.x;
    int v = (t < NBLK) ? part[t] : 0;
    s[t] = v;
    __syncthreads();
    for (int off = 1; off < 1024; off <<= 1) {
        int x = (t >= off) ? s[t - off] : 0;
        __syncthreads();
        s[t] += x;
        __syncthreads();
    }
    if (t < NBLK) part[t] = s[t] - v;  // exclusive
}

// Phase C: in-block exclusive scan + block base -> offsets and cursor copy
__global__ void k_scan_c(const int* __restrict__ cnt, const int* __restrict__ part,
                         int* __restrict__ offs, int* __restrict__ cur) {
    __shared__ int ws[4];
    int i = blockIdx.x * 256 + threadIdx.x;
    int v = (i < NTOT) ? cnt[i] : 0;
    int lane = threadIdx.x & 63, w = threadIdx.x >> 6;
    int x = v;
    for (int o = 1; o < 64; o <<= 1) {
        int y = __shfl_up(x, o, 64);
        if (lane >= o) x += y;
    }
    if (lane == 63) ws[w] = x;
    __syncthreads();
    int base = part[blockIdx.x];
    for (int k = 0; k < w; k++) base += ws[k];
    int excl = base + x - v;
    if (i < NTOT) { offs[i] = excl; cur[i] = excl; }
    if (i == 0) offs[NTOT] = NEDGE;
}

__global__ void k_scatter(const int* __restrict__ row, const int* __restrict__ col,
                          const float* __restrict__ val, int* __restrict__ cur,
                          int* __restrict__ ccol, float* __restrict__ cval) {
    int e = blockIdx.x * blockDim.x + threadIdx.x;
    if (e >= NEDGE) return;
    int r = row[e];
    int p = atomicAdd(&cur[r], 1);
    ccol[p] = col[e];
    cval[p] = val[e];
}

// front = (H + I) @ E : wave per row, lane per dim
__global__ void k_spmm(const float* __restrict__ E, const int* __restrict__ offs,
                       const int* __restrict__ ccol, const float* __restrict__ cval,
                       float* __restrict__ front) {
    int r = blockIdx.x * (blockDim.x >> 6) + (threadIdx.x >> 6);
    int d = threadIdx.x & 63;
    if (r >= NTOT) return;
    int s = offs[r], e = offs[r + 1];
    float acc = E[(size_t)r * D + d];
    for (int p = s; p < e; ++p) {
        int   c = ccol[p];
        float v = cval[p];
        acc += v * E[(size_t)c * D + d];
    }
    front[(size_t)r * D + d] = acc;
}

// Per-row: fc = lrelu(front@Wf^T + bf); back = lrelu((E*front)@Wb^T + bb);
// E_new = fc + back (in place, UNNORMALIZED for next layer);
// out chunk = E_new / max(||E_new||, eps).
//
// Round-5 lesson (rocprof): VALUBusy 17% + HBM 6% = latency-bound on weight
// reads. Wf+Wb (32KB) == L1 size; streaming front/E evicts them, so the
// 4.8GB/dispatch of per-thread weight re-reads hit L2 (~250cyc) -> stall.
// Fix: (a) stage Wf+Wb in LDS once per block (broadcast-pattern ds_read_b128,
// worst 2-way bank alias = free); (b) 2 rows per thread (r, r+16) so each
// weight ds_read feeds 2 rows' FMAs -> 4096 FMA vs 512 ds_read per thread.
// Quad-split layout kept: lane q=lane&3 owns K-quarter, g=lane>>2 row-in-wave,
// 2-step __shfl_xor quad reduce, redundant bias/lrelu/nsq (exact), q==0 lane
// stores unnormalized E, epilogue re-reads L1-hot E row for normalized out.
// Grid covers 128 rows/block; r0 always valid, only r1 needs tail guard.
__global__ __launch_bounds__(256, 4) void k_rowmv(
    const float* __restrict__ front, float* __restrict__ E,
    const float* __restrict__ Wf, const float* __restrict__ bfv,
    const float* __restrict__ Wb, const float* __restrict__ bbv,
    float* __restrict__ out, int chunk) {
    __shared__ float wfs[D * D];
    __shared__ float wbs[D * D];
    {
        int t = threadIdx.x;
        #pragma unroll
        for (int i = 0; i < 4; i++) {
            int idx = t * 16 + i * 4;
            *(float4*)(wfs + idx) = *(const float4*)(Wf + idx);
            *(float4*)(wbs + idx) = *(const float4*)(Wb + idx);
        }
    }
    __syncthreads();

    int lane = threadIdx.x & 63;
    int w    = threadIdx.x >> 6;
    int q    = lane & 3;        // K-quarter role
    int g    = lane >> 2;       // row-in-wave (0..15)
    int r0   = blockIdx.x * 128 + w * 32 + g;   // always < NTOT (grid exact)
    int r1   = r0 + 16;
    bool v1  = (r1 < NTOT);

    float f0[16], g0[16], f1[16], g1[16];
    {
        const float* fp = front + (size_t)r0 * D + q * 16;
        const float* ep = E     + (size_t)r0 * D + q * 16;
        #pragma unroll
        for (int i = 0; i < 4; i++) {
            float4 a = *(const float4*)(fp + i * 4);
            float4 b = *(const float4*)(ep + i * 4);
            f0[i*4+0] = a.x; f0[i*4+1] = a.y; f0[i*4+2] = a.z; f0[i*4+3] = a.w;
            g0[i*4+0] = a.x*b.x; g0[i*4+1] = a.y*b.y; g0[i*4+2] = a.z*b.z; g0[i*4+3] = a.w*b.w;
        }
    }
    if (v1) {
        const float* fp = front + (size_t)r1 * D + q * 16;
        const float* ep = E     + (size_t)r1 * D + q * 16;
        #pragma unroll
        for (int i = 0; i < 4; i++) {
            float4 a = *(const float4*)(fp + i * 4);
            float4 b = *(const float4*)(ep + i * 4);
            f1[i*4+0] = a.x; f1[i*4+1] = a.y; f1[i*4+2] = a.z; f1[i*4+3] = a.w;
            g1[i*4+0] = a.x*b.x; g1[i*4+1] = a.y*b.y; g1[i*4+2] = a.z*b.z; g1[i*4+3] = a.w*b.w;
        }
    } else {
        #pragma unroll
        for (int i = 0; i < 16; i++) { f1[i] = 0.f; g1[i] = 0.f; }
    }

    float nsq0 = 0.f, nsq1 = 0.f;
    float* erow0 = E + (size_t)r0 * D;
    float* erow1 = E + (size_t)r1 * D;
    #pragma unroll 1
    for (int j4 = 0; j4 < 16; j4++) {
        float ea[4], eb[4];
        #pragma unroll
        for (int jj = 0; jj < 4; jj++) {
            int j = j4 * 4 + jj;
            const float* wf = wfs + j * D + q * 16;
            const float* wb = wbs + j * D + q * 16;
            float aF0 = 0.f, aB0 = 0.f, aF1 = 0.f, aB1 = 0.f;
            #pragma unroll
            for (int i = 0; i < 4; i++) {
                float4 wv = *(const float4*)(wf + i * 4);
                aF0 = fmaf(wv.x, f0[i*4+0], aF0);
                aF0 = fmaf(wv.y, f0[i*4+1], aF0);
                aF0 = fmaf(wv.z, f0[i*4+2], aF0);
                aF0 = fmaf(wv.w, f0[i*4+3], aF0);
                aF1 = fmaf(wv.x, f1[i*4+0], aF1);
                aF1 = fmaf(wv.y, f1[i*4+1], aF1);
                aF1 = fmaf(wv.z, f1[i*4+2], aF1);
                aF1 = fmaf(wv.w, f1[i*4+3], aF1);
                float4 bv = *(const float4*)(wb + i * 4);
                aB0 = fmaf(bv.x, g0[i*4+0], aB0);
                aB0 = fmaf(bv.y, g0[i*4+1], aB0);
                aB0 = fmaf(bv.z, g0[i*4+2], aB0);
                aB0 = fmaf(bv.w, g0[i*4+3], aB0);
                aB1 = fmaf(bv.x, g1[i*4+0], aB1);
                aB1 = fmaf(bv.y, g1[i*4+1], aB1);
                aB1 = fmaf(bv.z, g1[i*4+2], aB1);
                aB1 = fmaf(bv.w, g1[i*4+3], aB1);
            }
            // quad tree-reduce: all 4 lanes end with the full K=64 sums
            aF0 += __shfl_xor(aF0, 1, 64); aF0 += __shfl_xor(aF0, 2, 64);
            aB0 += __shfl_xor(aB0, 1, 64); aB0 += __shfl_xor(aB0, 2, 64);
            aF1 += __shfl_xor(aF1, 1, 64); aF1 += __shfl_xor(aF1, 2, 64);
            aB1 += __shfl_xor(aB1, 1, 64); aB1 += __shfl_xor(aB1, 2, 64);
            float bF = bfv[j], bB = bbv[j];
            aF0 += bF; aB0 += bB; aF1 += bF; aB1 += bB;
            float vF0 = (aF0 > 0.f) ? aF0 : NEG * aF0;
            float vB0 = (aB0 > 0.f) ? aB0 : NEG * aB0;
            float vF1 = (aF1 > 0.f) ? aF1 : NEG * aF1;
            float vB1 = (aB1 > 0.f) ? aB1 : NEG * aB1;
            float e0 = vF0 + vB0;
            float e1 = vF1 + vB1;
            ea[jj] = e0; eb[jj] = e1;       // static index after unroll
            nsq0 += e0 * e0;                // identical across quad -> exact
            nsq1 += e1 * e1;
        }
        if (q == 0) {
            float4 u;
            u.x = ea[0]; u.y = ea[1]; u.z = ea[2]; u.w = ea[3];
            *(float4*)(erow0 + j4 * 4) = u;     // unnormalized E for next layer
            if (v1) {
                float4 s;
                s.x = eb[0]; s.y = eb[1]; s.z = eb[2]; s.w = eb[3];
                *(float4*)(erow1 + j4 * 4) = s;
            }
        }
    }

    float inv0 = 1.0f / fmaxf(sqrtf(nsq0), 1e-12f);
    float inv1 = 1.0f / fmaxf(sqrtf(nsq1), 1e-12f);
    // Re-read the just-written rows (L1/L2-hot) and emit normalized out chunk.
    {
        float* orow = out + (size_t)r0 * OUTD + (size_t)chunk * D;
        #pragma unroll
        for (int i = 0; i < 4; i++) {
            float4 u = *(const float4*)(erow0 + q * 16 + i * 4);
            float4 o;
            o.x = u.x * inv0; o.y = u.y * inv0; o.z = u.z * inv0; o.w = u.w * inv0;
            *(float4*)(orow + q * 16 + i * 4) = o;
        }
    }
    if (v1) {
        float* orow = out + (size_t)r1 * OUTD + (size_t)chunk * D;
        #pragma unroll
        for (int i = 0; i < 4; i++) {
            float4 u = *(const float4*)(erow1 + q * 16 + i * 4);
            float4 o;
            o.x = u.x * inv1; o.y = u.y * inv1; o.z = u.z * inv1; o.w = u.w * inv1;
            *(float4*)(orow + q * 16 + i * 4) = o;
        }
    }
}

extern "C" void kernel_launch(void* const* d_in, const int* in_sizes, int n_in,
                              void* d_out, int out_size, void* d_ws, size_t ws_size,
                              hipStream_t stream) {
    const float* ue   = (const float*)d_in[0];
    const float* ie   = (const float*)d_in[1];
    const int*   erow = (const int*)d_in[2];
    const int*   ecol = (const int*)d_in[3];
    const float* eval = (const float*)d_in[4];
    const float* Wf   = (const float*)d_in[5];
    const float* bfv  = (const float*)d_in[6];
    const float* Wb   = (const float*)d_in[7];
    const float* bbv  = (const float*)d_in[8];
    float* out = (float*)d_out;

    float* E     = (float*)d_ws;                    // NTOT*D
    float* front = E + (size_t)NTOT * D;            // NTOT*D
    float* invn  = front + (size_t)NTOT * D;        // NTOT (unused now, kept for layout)
    int*   cnt   = (int*)(invn + NTOT);             // NTOT
    int*   offs  = cnt + NTOT;                      // NTOT+1
    int*   cur   = offs + NTOT + 1;                 // NTOT
    int*   part  = cur + NTOT;                      // 1024
    int*   ccol  = part + 1024;                     // NEDGE
    float* cval  = (float*)(ccol + NEDGE);          // NEDGE

    hipMemsetAsync(cnt, 0, NTOT * sizeof(int), stream);
    k_init<<<(NTOT * 16 + 255) / 256, 256, 0, stream>>>(ue, ie, E, out);
    k_hist<<<(NEDGE + 255) / 256, 256, 0, stream>>>(erow, cnt);
    k_scan_a<<<NBLK, 256, 0, stream>>>(cnt, part);
    k_scan_b<<<1, 1024, 0, stream>>>(part);
    k_scan_c<<<NBLK, 256, 0, stream>>>(cnt, part, offs, cur);
    k_scatter<<<(NEDGE + 255) / 256, 256, 0, stream>>>(erow, ecol, eval, cur, ccol, cval);

    for (int i = 0; i < 3; i++) {
        k_spmm<<<(NTOT + 3) / 4, 256, 0, stream>>>(E, offs, ccol, cval, front);
        k_rowmv<<<(NTOT + 127) / 128, 256, 0, stream>>>(
            front, E, Wf + (size_t)i * D * D, bfv + (size_t)i * D,
            Wb + (size_t)i * D * D, bbv + (size_t)i * D, out, i + 1);
    }
}

// Round 4
// 979.455 us; speedup vs baseline: 2.5676x; 2.5676x over previous
//
#include <hip/hip_runtime.h>
#include <hip/hip_bf16.h>
#include <stdint.h>

#define N_USER 100000
#define N_ITEM 50000
#define NTOT   150000
#define NEDGE  1200000
#define D      64
#define OUTD   256
#define NEG    0.01f
#define NBLK   586   // ceil(150000/256)
#define WPLANE 1028  // LDS plane stride (floats): 64*16 + 4 -> q-planes hit disjoint banks

// Build E = concat(user_emb, item_emb) and write output chunk 0 (raw emb, fp32)
__global__ void k_init(const float* __restrict__ ue, const float* __restrict__ ie,
                       float* __restrict__ E, float* __restrict__ out) {
    int t = blockIdx.x * blockDim.x + threadIdx.x;
    if (t >= NTOT * 16) return;
    int r = t >> 4, q = t & 15;
    const float* src = (r < N_USER) ? (ue + (size_t)r * D)
                                    : (ie + (size_t)(r - N_USER) * D);
    float4 v = *(const float4*)(src + q * 4);
    *(float4*)(E + (size_t)r * D + q * 4) = v;
    *(float4*)(out + (size_t)r * OUTD + q * 4) = v;
}

__global__ void k_hist(const int* __restrict__ row, int* __restrict__ cnt) {
    int e = blockIdx.x * blockDim.x + threadIdx.x;
    if (e < NEDGE) atomicAdd(&cnt[row[e]], 1);
}

// Phase A: per-block (256) partial sums of counts
__global__ void k_scan_a(const int* __restrict__ cnt, int* __restrict__ part) {
    __shared__ int s[4];
    int i = blockIdx.x * 256 + threadIdx.x;
    int v = (i < NTOT) ? cnt[i] : 0;
    for (int off = 32; off; off >>= 1) v += __shfl_down(v, off, 64);
    if ((threadIdx.x & 63) == 0) s[threadIdx.x >> 6] = v;
    __syncthreads();
    if (threadIdx.x == 0) part[blockIdx.x] = s[0] + s[1] + s[2] + s[3];
}

// Phase B: single-block exclusive scan of NBLK partials
__global__ void k_scan_b(int* __restrict__ part) {
    __shared__ int s[1024];
    int t = threadIdx.x;
    int v = (t < NBLK) ? part[t] : 0;
    s[t] = v;
    __syncthreads();
    for (int off = 1; off < 1024; off <<= 1) {
        int x = (t >= off) ? s[t - off] : 0;
        __syncthreads();
        s[t] += x;
        __syncthreads();
    }
    if (t < NBLK) part[t] = s[t] - v;  // exclusive
}

// Phase C: in-block exclusive scan + block base -> offsets and cursor copy
__global__ void k_scan_c(const int* __restrict__ cnt, const int* __restrict__ part,
                         int* __restrict__ offs, int* __restrict__ cur) {
    __shared__ int ws[4];
    int i = blockIdx.x * 256 + threadIdx.x;
    int v = (i < NTOT) ? cnt[i] : 0;
    int lane = threadIdx.x & 63, w = threadIdx.x >> 6;
    int x = v;
    for (int o = 1; o < 64; o <<= 1) {
        int y = __shfl_up(x, o, 64);
        if (lane >= o) x += y;
    }
    if (lane == 63) ws[w] = x;
    __syncthreads();
    int base = part[blockIdx.x];
    for (int k = 0; k < w; k++) base += ws[k];
    int excl = base + x - v;
    if (i < NTOT) { offs[i] = excl; cur[i] = excl; }
    if (i == 0) offs[NTOT] = NEDGE;
}

__global__ void k_scatter(const int* __restrict__ row, const int* __restrict__ col,
                          const float* __restrict__ val, int* __restrict__ cur,
                          int* __restrict__ ccol, float* __restrict__ cval) {
    int e = blockIdx.x * blockDim.x + threadIdx.x;
    if (e >= NEDGE) return;
    int r = row[e];
    int p = atomicAdd(&cur[r], 1);
    ccol[p] = col[e];
    cval[p] = val[e];
}

// front = (H + I) @ E : wave per row, lane per dim
__global__ void k_spmm(const float* __restrict__ E, const int* __restrict__ offs,
                       const int* __restrict__ ccol, const float* __restrict__ cval,
                       float* __restrict__ front) {
    int r = blockIdx.x * (blockDim.x >> 6) + (threadIdx.x >> 6);
    int d = threadIdx.x & 63;
    if (r >= NTOT) return;
    int s = offs[r], e = offs[r + 1];
    float acc = E[(size_t)r * D + d];
    for (int p = s; p < e; ++p) {
        int   c = ccol[p];
        float v = cval[p];
        acc += v * E[(size_t)c * D + d];
    }
    front[(size_t)r * D + d] = acc;
}

// Per-row: fc = lrelu(front@Wf^T + bf); back = lrelu((E*front)@Wb^T + bb);
// E_new = fc + back (in place, UNNORMALIZED for next layer);
// out chunk = E_new / max(||E_new||, eps).
//
// Round-3 lesson: quad-split, 1 row/lane, 32 floats live state = the ONLY
// config this toolchain keeps in registers (64 VGPR, zero spill). 2 rows
// (64 floats) spilled -> 1.59GB scratch fetch. Round-2 lesson: weights from
// global are L2-latency-bound (~500cyc/load, L1 thrashed by streams).
// This round: weights staged in LDS ONCE per block, PLANE-PADDED layout:
//   w[q-plane][j*16 + k],  plane stride 1028 floats
// so the 4 q-groups' ds_read_b128 addresses land on disjoint 4-bank spans
// (round-3's j*64+q*16 layout had q0/q2 on the same banks -> 11.7M conflicts).
// Weight staging is a one-time ~100cyc cost per block; bias loads stay
// wave-uniform s_loads from global. No waves-per-EU hint (round-2's (256,4)
// appeared to cap residency at 4 waves/EU -> nothing hid latency).
__global__ __launch_bounds__(256) void k_rowmv(
    const float* __restrict__ front, float* __restrict__ E,
    const float* __restrict__ Wf, const float* __restrict__ bfv,
    const float* __restrict__ Wb, const float* __restrict__ bbv,
    float* __restrict__ out, int chunk) {
    __shared__ float wfs[4 * WPLANE];
    __shared__ float wbs[4 * WPLANE];
    {
        // 256 threads stage 256 (j,kq) pairs of 16 floats each, both matrices.
        int t  = threadIdx.x;
        int j  = t >> 2;
        int kq = t & 3;
        const float* fsrc = Wf + (size_t)j * D + kq * 16;
        const float* bsrc = Wb + (size_t)j * D + kq * 16;
        float* fdst = wfs + kq * WPLANE + j * 16;
        float* bdst = wbs + kq * WPLANE + j * 16;
        #pragma unroll
        for (int i = 0; i < 4; i++) {
            *(float4*)(fdst + i * 4) = *(const float4*)(fsrc + i * 4);
            *(float4*)(bdst + i * 4) = *(const float4*)(bsrc + i * 4);
        }
    }
    __syncthreads();   // before any early return

    int lane = threadIdx.x & 63;
    int w    = threadIdx.x >> 6;
    int q    = lane & 3;        // K-quarter role
    int g    = lane >> 2;       // row-in-wave (0..15)
    int r    = blockIdx.x * 64 + w * 16 + g;
    if (r >= NTOT) return;

    // Load this lane's K-quarter of front (f) and E*front (gg)
    float f[16], gg[16];
    const float* fp = front + (size_t)r * D + q * 16;
    const float* ep = E     + (size_t)r * D + q * 16;
    #pragma unroll
    for (int i = 0; i < 4; i++) {
        float4 a = *(const float4*)(fp + i * 4);
        float4 b = *(const float4*)(ep + i * 4);
        f[i*4+0] = a.x; f[i*4+1] = a.y; f[i*4+2] = a.z; f[i*4+3] = a.w;
        gg[i*4+0] = a.x*b.x; gg[i*4+1] = a.y*b.y; gg[i*4+2] = a.z*b.z; gg[i*4+3] = a.w*b.w;
    }

    const float* wfq = wfs + q * WPLANE;
    const float* wbq = wbs + q * WPLANE;

    float nsq = 0.f;
    float* erow = E + (size_t)r * D;
    #pragma unroll 1
    for (int j4 = 0; j4 < 16; j4++) {
        float e4[4];
        #pragma unroll
        for (int jj = 0; jj < 4; jj++) {
            int j = j4 * 4 + jj;
            const float* wf = wfq + j * 16;
            const float* wb = wbq + j * 16;
            float aF = 0.f, aB = 0.f;
            #pragma unroll
            for (int i = 0; i < 4; i++) {
                float4 wv = *(const float4*)(wf + i * 4);
                aF = fmaf(wv.x, f[i*4+0], aF);
                aF = fmaf(wv.y, f[i*4+1], aF);
                aF = fmaf(wv.z, f[i*4+2], aF);
                aF = fmaf(wv.w, f[i*4+3], aF);
                float4 bv = *(const float4*)(wb + i * 4);
                aB = fmaf(bv.x, gg[i*4+0], aB);
                aB = fmaf(bv.y, gg[i*4+1], aB);
                aB = fmaf(bv.z, gg[i*4+2], aB);
                aB = fmaf(bv.w, gg[i*4+3], aB);
            }
            // quad tree-reduce: all 4 lanes end with the full K=64 sum
            aF += __shfl_xor(aF, 1, 64);
            aF += __shfl_xor(aF, 2, 64);
            aB += __shfl_xor(aB, 1, 64);
            aB += __shfl_xor(aB, 2, 64);
            aF += bfv[j];
            aB += bbv[j];
            float vF = (aF > 0.f) ? aF : NEG * aF;
            float vB = (aB > 0.f) ? aB : NEG * aB;
            float e = vF + vB;
            e4[jj] = e;          // static index after unroll
            nsq += e * e;        // identical across the quad -> exact row norm
        }
        if (q == 0) {
            float4 u;
            u.x = e4[0]; u.y = e4[1]; u.z = e4[2]; u.w = e4[3];
            *(float4*)(erow + j4 * 4) = u;   // unnormalized E for next layer
        }
    }

    float inv = 1.0f / fmaxf(sqrtf(nsq), 1e-12f);
    // Re-read the just-written row (L1/L2-hot) and emit normalized out chunk.
    float* orow = out + (size_t)r * OUTD + (size_t)chunk * D;
    #pragma unroll
    for (int i = 0; i < 4; i++) {
        float4 u = *(const float4*)(erow + q * 16 + i * 4);
        float4 o;
        o.x = u.x * inv; o.y = u.y * inv; o.z = u.z * inv; o.w = u.w * inv;
        *(float4*)(orow + q * 16 + i * 4) = o;
    }
}

extern "C" void kernel_launch(void* const* d_in, const int* in_sizes, int n_in,
                              void* d_out, int out_size, void* d_ws, size_t ws_size,
                              hipStream_t stream) {
    const float* ue   = (const float*)d_in[0];
    const float* ie   = (const float*)d_in[1];
    const int*   erow = (const int*)d_in[2];
    const int*   ecol = (const int*)d_in[3];
    const float* eval = (const float*)d_in[4];
    const float* Wf   = (const float*)d_in[5];
    const float* bfv  = (const float*)d_in[6];
    const float* Wb   = (const float*)d_in[7];
    const float* bbv  = (const float*)d_in[8];
    float* out = (float*)d_out;

    float* E     = (float*)d_ws;                    // NTOT*D
    float* front = E + (size_t)NTOT * D;            // NTOT*D
    float* invn  = front + (size_t)NTOT * D;        // NTOT (unused now, kept for layout)
    int*   cnt   = (int*)(invn + NTOT);             // NTOT
    int*   offs  = cnt + NTOT;                      // NTOT+1
    int*   cur   = offs + NTOT + 1;                 // NTOT
    int*   part  = cur + NTOT;                      // 1024
    int*   ccol  = part + 1024;                     // NEDGE
    float* cval  = (float*)(ccol + NEDGE);          // NEDGE

    hipMemsetAsync(cnt, 0, NTOT * sizeof(int), stream);
    k_init<<<(NTOT * 16 + 255) / 256, 256, 0, stream>>>(ue, ie, E, out);
    k_hist<<<(NEDGE + 255) / 256, 256, 0, stream>>>(erow, cnt);
    k_scan_a<<<NBLK, 256, 0, stream>>>(cnt, part);
    k_scan_b<<<1, 1024, 0, stream>>>(part);
    k_scan_c<<<NBLK, 256, 0, stream>>>(cnt, part, offs, cur);
    k_scatter<<<(NEDGE + 255) / 256, 256, 0, stream>>>(erow, ecol, eval, cur, ccol, cval);

    for (int i = 0; i < 3; i++) {
        k_spmm<<<(NTOT + 3) / 4, 256, 0, stream>>>(E, offs, ccol, cval, front);
        k_rowmv<<<(NTOT + 63) / 64, 256, 0, stream>>>(
            front, E, Wf + (size_t)i * D * D, bfv + (size_t)i * D,
            Wb + (size_t)i * D * D, bbv + (size_t)i * D, out, i + 1);
    }
}

// Round 5
// 831.739 us; speedup vs baseline: 3.0236x; 1.1776x over previous
//
#include <hip/hip_runtime.h>
#include <hip/hip_bf16.h>
#include <stdint.h>

#define N_USER 100000
#define N_ITEM 50000
#define NTOT   150000
#define NEDGE  1200000
#define D      64
#define OUTD   256
#define NEG    0.01f
#define NBLK   586   // ceil(150000/256)
#define WPLANE 1028  // LDS plane stride (floats): 64*16 + 4 -> q-planes hit disjoint banks

// Build E = concat(user_emb, item_emb) and write output chunk 0 (raw emb, fp32)
__global__ void k_init(const float* __restrict__ ue, const float* __restrict__ ie,
                       float* __restrict__ E, float* __restrict__ out) {
    int t = blockIdx.x * blockDim.x + threadIdx.x;
    if (t >= NTOT * 16) return;
    int r = t >> 4, q = t & 15;
    const float* src = (r < N_USER) ? (ue + (size_t)r * D)
                                    : (ie + (size_t)(r - N_USER) * D);
    float4 v = *(const float4*)(src + q * 4);
    *(float4*)(E + (size_t)r * D + q * 4) = v;
    *(float4*)(out + (size_t)r * OUTD + q * 4) = v;
}

__global__ void k_hist(const int* __restrict__ row, int* __restrict__ cnt) {
    int e = blockIdx.x * blockDim.x + threadIdx.x;
    if (e < NEDGE) atomicAdd(&cnt[row[e]], 1);
}

// Phase A: per-block (256) partial sums of counts
__global__ void k_scan_a(const int* __restrict__ cnt, int* __restrict__ part) {
    __shared__ int s[4];
    int i = blockIdx.x * 256 + threadIdx.x;
    int v = (i < NTOT) ? cnt[i] : 0;
    for (int off = 32; off; off >>= 1) v += __shfl_down(v, off, 64);
    if ((threadIdx.x & 63) == 0) s[threadIdx.x >> 6] = v;
    __syncthreads();
    if (threadIdx.x == 0) part[blockIdx.x] = s[0] + s[1] + s[2] + s[3];
}

// Phase B: single-block exclusive scan of NBLK partials
__global__ void k_scan_b(int* __restrict__ part) {
    __shared__ int s[1024];
    int t = threadIdx.x;
    int v = (t < NBLK) ? part[t] : 0;
    s[t] = v;
    __syncthreads();
    for (int off = 1; off < 1024; off <<= 1) {
        int x = (t >= off) ? s[t - off] : 0;
        __syncthreads();
        s[t] += x;
        __syncthreads();
    }
    if (t < NBLK) part[t] = s[t] - v;  // exclusive
}

// Phase C: in-block exclusive scan + block base -> offsets and cursor copy
__global__ void k_scan_c(const int* __restrict__ cnt, const int* __restrict__ part,
                         int* __restrict__ offs, int* __restrict__ cur) {
    __shared__ int ws[4];
    int i = blockIdx.x * 256 + threadIdx.x;
    int v = (i < NTOT) ? cnt[i] : 0;
    int lane = threadIdx.x & 63, w = threadIdx.x >> 6;
    int x = v;
    for (int o = 1; o < 64; o <<= 1) {
        int y = __shfl_up(x, o, 64);
        if (lane >= o) x += y;
    }
    if (lane == 63) ws[w] = x;
    __syncthreads();
    int base = part[blockIdx.x];
    for (int k = 0; k < w; k++) base += ws[k];
    int excl = base + x - v;
    if (i < NTOT) { offs[i] = excl; cur[i] = excl; }
    if (i == 0) offs[NTOT] = NEDGE;
}

// Scatter edges into CSR order as fused (col, val) int2 pairs:
// one 8B store per edge; spmm later does one 8B load per edge.
__global__ void k_scatter(const int* __restrict__ row, const int* __restrict__ col,
                          const float* __restrict__ val, int* __restrict__ cur,
                          int2* __restrict__ ce) {
    int e = blockIdx.x * blockDim.x + threadIdx.x;
    if (e >= NEDGE) return;
    int r = row[e];
    int p = atomicAdd(&cur[r], 1);
    int2 u;
    u.x = col[e];
    u.y = __float_as_int(val[e]);
    ce[p] = u;
}

// front = (H + I) @ E : wave per row, lane per dim.
// Round-6 lesson (rocprof): VALUBusy 16% + HBM 21% at 70% occupancy =
// latency-bound on the SERIAL edge chain (load col -> gather E row -> fma,
// ~8 dependent L2/L3 round trips per row, avg degree 8). Fix: 4-way ILP —
// batch-load 4 (col,val) int2 pairs, issue 4 independent gathers, 4
// independent accumulators; compiler batches the waitcnts so 4 gathers are
// in flight per wave. Summation-order change is within tolerance (the
// reference's segment_sum order differs anyway).
__global__ void k_spmm(const float* __restrict__ E, const int* __restrict__ offs,
                       const int2* __restrict__ ce, float* __restrict__ front) {
    int r = blockIdx.x * (blockDim.x >> 6) + (threadIdx.x >> 6);
    int d = threadIdx.x & 63;
    if (r >= NTOT) return;
    int s = offs[r], e = offs[r + 1];
    float acc = E[(size_t)r * D + d];
    float a0 = 0.f, a1 = 0.f, a2 = 0.f, a3 = 0.f;
    int p = s;
    for (; p + 4 <= e; p += 4) {
        int2 c0 = ce[p + 0];
        int2 c1 = ce[p + 1];
        int2 c2 = ce[p + 2];
        int2 c3 = ce[p + 3];
        float x0 = E[(size_t)c0.x * D + d];
        float x1 = E[(size_t)c1.x * D + d];
        float x2 = E[(size_t)c2.x * D + d];
        float x3 = E[(size_t)c3.x * D + d];
        a0 = fmaf(__int_as_float(c0.y), x0, a0);
        a1 = fmaf(__int_as_float(c1.y), x1, a1);
        a2 = fmaf(__int_as_float(c2.y), x2, a2);
        a3 = fmaf(__int_as_float(c3.y), x3, a3);
    }
    for (; p < e; ++p) {
        int2 c = ce[p];
        acc = fmaf(__int_as_float(c.y), E[(size_t)c.x * D + d], acc);
    }
    acc += (a0 + a1) + (a2 + a3);
    front[(size_t)r * D + d] = acc;
}

// Per-row: fc = lrelu(front@Wf^T + bf); back = lrelu((E*front)@Wb^T + bb);
// E_new = fc + back (in place, UNNORMALIZED for next layer);
// out chunk = E_new / max(||E_new||, eps).
//
// Round-3 lesson: quad-split, 1 row/lane, 32 floats live state = the ONLY
// config this toolchain keeps in registers (64 VGPR, zero spill). 2 rows
// (64 floats) spilled -> 1.59GB scratch fetch. Round-2 lesson: weights from
// global are L2-latency-bound (~500cyc/load, L1 thrashed by streams).
// Weights staged in LDS ONCE per block, PLANE-PADDED layout:
//   w[q-plane][j*16 + k],  plane stride 1028 floats
// so the 4 q-groups' ds_read_b128 addresses land on disjoint 4-bank spans.
// Verified round 4: conflicts ~0, no spill, k_rowmv off the top-5.
__global__ __launch_bounds__(256) void k_rowmv(
    const float* __restrict__ front, float* __restrict__ E,
    const float* __restrict__ Wf, const float* __restrict__ bfv,
    const float* __restrict__ Wb, const float* __restrict__ bbv,
    float* __restrict__ out, int chunk) {
    __shared__ float wfs[4 * WPLANE];
    __shared__ float wbs[4 * WPLANE];
    {
        // 256 threads stage 256 (j,kq) pairs of 16 floats each, both matrices.
        int t  = threadIdx.x;
        int j  = t >> 2;
        int kq = t & 3;
        const float* fsrc = Wf + (size_t)j * D + kq * 16;
        const float* bsrc = Wb + (size_t)j * D + kq * 16;
        float* fdst = wfs + kq * WPLANE + j * 16;
        float* bdst = wbs + kq * WPLANE + j * 16;
        #pragma unroll
        for (int i = 0; i < 4; i++) {
            *(float4*)(fdst + i * 4) = *(const float4*)(fsrc + i * 4);
            *(float4*)(bdst + i * 4) = *(const float4*)(bsrc + i * 4);
        }
    }
    __syncthreads();   // before any early return

    int lane = threadIdx.x & 63;
    int w    = threadIdx.x >> 6;
    int q    = lane & 3;        // K-quarter role
    int g    = lane >> 2;       // row-in-wave (0..15)
    int r    = blockIdx.x * 64 + w * 16 + g;
    if (r >= NTOT) return;

    // Load this lane's K-quarter of front (f) and E*front (gg)
    float f[16], gg[16];
    const float* fp = front + (size_t)r * D + q * 16;
    const float* ep = E     + (size_t)r * D + q * 16;
    #pragma unroll
    for (int i = 0; i < 4; i++) {
        float4 a = *(const float4*)(fp + i * 4);
        float4 b = *(const float4*)(ep + i * 4);
        f[i*4+0] = a.x; f[i*4+1] = a.y; f[i*4+2] = a.z; f[i*4+3] = a.w;
        gg[i*4+0] = a.x*b.x; gg[i*4+1] = a.y*b.y; gg[i*4+2] = a.z*b.z; gg[i*4+3] = a.w*b.w;
    }

    const float* wfq = wfs + q * WPLANE;
    const float* wbq = wbs + q * WPLANE;

    float nsq = 0.f;
    float* erow = E + (size_t)r * D;
    #pragma unroll 1
    for (int j4 = 0; j4 < 16; j4++) {
        float e4[4];
        #pragma unroll
        for (int jj = 0; jj < 4; jj++) {
            int j = j4 * 4 + jj;
            const float* wf = wfq + j * 16;
            const float* wb = wbq + j * 16;
            float aF = 0.f, aB = 0.f;
            #pragma unroll
            for (int i = 0; i < 4; i++) {
                float4 wv = *(const float4*)(wf + i * 4);
                aF = fmaf(wv.x, f[i*4+0], aF);
                aF = fmaf(wv.y, f[i*4+1], aF);
                aF = fmaf(wv.z, f[i*4+2], aF);
                aF = fmaf(wv.w, f[i*4+3], aF);
                float4 bv = *(const float4*)(wb + i * 4);
                aB = fmaf(bv.x, gg[i*4+0], aB);
                aB = fmaf(bv.y, gg[i*4+1], aB);
                aB = fmaf(bv.z, gg[i*4+2], aB);
                aB = fmaf(bv.w, gg[i*4+3], aB);
            }
            // quad tree-reduce: all 4 lanes end with the full K=64 sum
            aF += __shfl_xor(aF, 1, 64);
            aF += __shfl_xor(aF, 2, 64);
            aB += __shfl_xor(aB, 1, 64);
            aB += __shfl_xor(aB, 2, 64);
            aF += bfv[j];
            aB += bbv[j];
            float vF = (aF > 0.f) ? aF : NEG * aF;
            float vB = (aB > 0.f) ? aB : NEG * aB;
            float e = vF + vB;
            e4[jj] = e;          // static index after unroll
            nsq += e * e;        // identical across the quad -> exact row norm
        }
        if (q == 0) {
            float4 u;
            u.x = e4[0]; u.y = e4[1]; u.z = e4[2]; u.w = e4[3];
            *(float4*)(erow + j4 * 4) = u;   // unnormalized E for next layer
        }
    }

    float inv = 1.0f / fmaxf(sqrtf(nsq), 1e-12f);
    // Re-read the just-written row (L1/L2-hot) and emit normalized out chunk.
    float* orow = out + (size_t)r * OUTD + (size_t)chunk * D;
    #pragma unroll
    for (int i = 0; i < 4; i++) {
        float4 u = *(const float4*)(erow + q * 16 + i * 4);
        float4 o;
        o.x = u.x * inv; o.y = u.y * inv; o.z = u.z * inv; o.w = u.w * inv;
        *(float4*)(orow + q * 16 + i * 4) = o;
    }
}

extern "C" void kernel_launch(void* const* d_in, const int* in_sizes, int n_in,
                              void* d_out, int out_size, void* d_ws, size_t ws_size,
                              hipStream_t stream) {
    const float* ue   = (const float*)d_in[0];
    const float* ie   = (const float*)d_in[1];
    const int*   erow = (const int*)d_in[2];
    const int*   ecol = (const int*)d_in[3];
    const float* eval = (const float*)d_in[4];
    const float* Wf   = (const float*)d_in[5];
    const float* bfv  = (const float*)d_in[6];
    const float* Wb   = (const float*)d_in[7];
    const float* bbv  = (const float*)d_in[8];
    float* out = (float*)d_out;

    float* E     = (float*)d_ws;                    // NTOT*D
    float* front = E + (size_t)NTOT * D;            // NTOT*D
    float* invn  = front + (size_t)NTOT * D;        // NTOT (unused now, kept for layout)
    int*   cnt   = (int*)(invn + NTOT);             // NTOT
    int*   offs  = cnt + NTOT;                      // NTOT+1
    int*   cur   = offs + NTOT + 1;                 // NTOT
    int*   part  = cur + NTOT;                      // 1024
    int2*  ce    = (int2*)(part + 1024);            // NEDGE int2 (col,val)

    hipMemsetAsync(cnt, 0, NTOT * sizeof(int), stream);
    k_init<<<(NTOT * 16 + 255) / 256, 256, 0, stream>>>(ue, ie, E, out);
    k_hist<<<(NEDGE + 255) / 256, 256, 0, stream>>>(erow, cnt);
    k_scan_a<<<NBLK, 256, 0, stream>>>(cnt, part);
    k_scan_b<<<1, 1024, 0, stream>>>(part);
    k_scan_c<<<NBLK, 256, 0, stream>>>(cnt, part, offs, cur);
    k_scatter<<<(NEDGE + 255) / 256, 256, 0, stream>>>(erow, ecol, eval, cur, ce);

    for (int i = 0; i < 3; i++) {
        k_spmm<<<(NTOT + 3) / 4, 256, 0, stream>>>(E, offs, ce, front);
        k_rowmv<<<(NTOT + 63) / 64, 256, 0, stream>>>(
            front, E, Wf + (size_t)i * D * D, bfv + (size_t)i * D,
            Wb + (size_t)i * D * D, bbv + (size_t)i * D, out, i + 1);
    }
}

// Round 6
// 700.700 us; speedup vs baseline: 3.5891x; 1.1870x over previous
//
#include <hip/hip_runtime.h>
#include <hip/hip_bf16.h>
#include <stdint.h>

#define N_USER 100000
#define N_ITEM 50000
#define NTOT   150000
#define NEDGE  1200000
#define D      64
#define OUTD   256
#define NEG    0.01f
#define NBLK   586   // ceil(150000/256)
#define LSTR   65    // LDS row stride (floats): 64+1 -> frag reads <=2-way bank alias

typedef __attribute__((ext_vector_type(8))) short short8;
typedef __attribute__((ext_vector_type(4))) float f32x4;

// fp32 -> bf16 (RNE), returns the 16-bit pattern.
__device__ inline ushort f2bf(float x) {
    uint32_t u = __float_as_uint(x);
    u += 0x7fffu + ((u >> 16) & 1u);
    return (ushort)(u >> 16);
}
// x ~= hi + lo with hi,lo bf16. Combined rel error ~2^-17.
__device__ inline void split2(float x, ushort& h, ushort& l) {
    ushort hh = f2bf(x);
    float hf = __uint_as_float(((uint32_t)hh) << 16);
    h = hh;
    l = f2bf(x - hf);
}
// Load 8 contiguous floats, produce hi/lo bf16 fragments.
__device__ inline void split8(const float* p, short8& h8, short8& l8) {
    float4 v0 = *(const float4*)p;
    float4 v1 = *(const float4*)(p + 4);
    float vv[8] = {v0.x, v0.y, v0.z, v0.w, v1.x, v1.y, v1.z, v1.w};
    #pragma unroll
    for (int e = 0; e < 8; e++) {
        ushort h, l;
        split2(vv[e], h, l);
        h8[e] = (short)h; l8[e] = (short)l;
    }
}

// Build E = concat(user_emb, item_emb) and write output chunk 0 (raw emb, fp32)
__global__ void k_init(const float* __restrict__ ue, const float* __restrict__ ie,
                       float* __restrict__ E, float* __restrict__ out) {
    int t = blockIdx.x * blockDim.x + threadIdx.x;
    if (t >= NTOT * 16) return;
    int r = t >> 4, q = t & 15;
    const float* src = (r < N_USER) ? (ue + (size_t)r * D)
                                    : (ie + (size_t)(r - N_USER) * D);
    float4 v = *(const float4*)(src + q * 4);
    *(float4*)(E + (size_t)r * D + q * 4) = v;
    *(float4*)(out + (size_t)r * OUTD + q * 4) = v;
}

__global__ void k_hist(const int* __restrict__ row, int* __restrict__ cnt) {
    int e = blockIdx.x * blockDim.x + threadIdx.x;
    if (e < NEDGE) atomicAdd(&cnt[row[e]], 1);
}

// Phase A: per-block (256) partial sums of counts
__global__ void k_scan_a(const int* __restrict__ cnt, int* __restrict__ part) {
    __shared__ int s[4];
    int i = blockIdx.x * 256 + threadIdx.x;
    int v = (i < NTOT) ? cnt[i] : 0;
    for (int off = 32; off; off >>= 1) v += __shfl_down(v, off, 64);
    if ((threadIdx.x & 63) == 0) s[threadIdx.x >> 6] = v;
    __syncthreads();
    if (threadIdx.x == 0) part[blockIdx.x] = s[0] + s[1] + s[2] + s[3];
}

// Phase B: single-block exclusive scan of NBLK partials
__global__ void k_scan_b(int* __restrict__ part) {
    __shared__ int s[1024];
    int t = threadIdx.x;
    int v = (t < NBLK) ? part[t] : 0;
    s[t] = v;
    __syncthreads();
    for (int off = 1; off < 1024; off <<= 1) {
        int x = (t >= off) ? s[t - off] : 0;
        __syncthreads();
        s[t] += x;
        __syncthreads();
    }
    if (t < NBLK) part[t] = s[t] - v;  // exclusive
}

// Phase C: in-block exclusive scan + block base -> offsets and cursor copy
__global__ void k_scan_c(const int* __restrict__ cnt, const int* __restrict__ part,
                         int* __restrict__ offs, int* __restrict__ cur) {
    __shared__ int ws[4];
    int i = blockIdx.x * 256 + threadIdx.x;
    int v = (i < NTOT) ? cnt[i] : 0;
    int lane = threadIdx.x & 63, w = threadIdx.x >> 6;
    int x = v;
    for (int o = 1; o < 64; o <<= 1) {
        int y = __shfl_up(x, o, 64);
        if (lane >= o) x += y;
    }
    if (lane == 63) ws[w] = x;
    __syncthreads();
    int base = part[blockIdx.x];
    for (int k = 0; k < w; k++) base += ws[k];
    int excl = base + x - v;
    if (i < NTOT) { offs[i] = excl; cur[i] = excl; }
    if (i == 0) offs[NTOT] = NEDGE;
}

// Scatter edges into CSR order as fused (col, val) int2 pairs.
__global__ void k_scatter(const int* __restrict__ row, const int* __restrict__ col,
                          const float* __restrict__ val, int* __restrict__ cur,
                          int2* __restrict__ ce) {
    int e = blockIdx.x * blockDim.x + threadIdx.x;
    if (e >= NEDGE) return;
    int r = row[e];
    int p = atomicAdd(&cur[r], 1);
    int2 u;
    u.x = col[e];
    u.y = __float_as_int(val[e]);
    ce[p] = u;
}

// front = (H + I) @ E : wave per row, lane per dim, 4-way edge ILP (round 5).
__global__ void k_spmm(const float* __restrict__ E, const int* __restrict__ offs,
                       const int2* __restrict__ ce, float* __restrict__ front) {
    int r = blockIdx.x * (blockDim.x >> 6) + (threadIdx.x >> 6);
    int d = threadIdx.x & 63;
    if (r >= NTOT) return;
    int s = offs[r], e = offs[r + 1];
    float acc = E[(size_t)r * D + d];
    float a0 = 0.f, a1 = 0.f, a2 = 0.f, a3 = 0.f;
    int p = s;
    for (; p + 4 <= e; p += 4) {
        int2 c0 = ce[p + 0];
        int2 c1 = ce[p + 1];
        int2 c2 = ce[p + 2];
        int2 c3 = ce[p + 3];
        float x0 = E[(size_t)c0.x * D + d];
        float x1 = E[(size_t)c1.x * D + d];
        float x2 = E[(size_t)c2.x * D + d];
        float x3 = E[(size_t)c3.x * D + d];
        a0 = fmaf(__int_as_float(c0.y), x0, a0);
        a1 = fmaf(__int_as_float(c1.y), x1, a1);
        a2 = fmaf(__int_as_float(c2.y), x2, a2);
        a3 = fmaf(__int_as_float(c3.y), x3, a3);
    }
    for (; p < e; ++p) {
        int2 c = ce[p];
        acc = fmaf(__int_as_float(c.y), E[(size_t)c.x * D + d], acc);
    }
    acc += (a0 + a1) + (a2 + a3);
    front[(size_t)r * D + d] = acc;
}

// Per-row: fc = lrelu(front@Wf^T + bf); back = lrelu((E*front)@Wb^T + bb);
// E_new = fc + back (in place, UNNORMALIZED); out chunk = E_new/max(||E_new||,eps).
//
// Round-6 lesson (rocprof): the quad-split VALU version was LDS-read-bound:
// 512 ds_read_b128/thread (16-way broadcast wastes 15/16 of each read) ->
// model 94us ~= measured 111us, VALUBusy 51%, MfmaUtil 0. Fix: MFMA.
//   - fp32 = bf16_hi + bf16_lo split; 3 passes (hi*hi + lo*hi + hi*lo),
//     dropped lo*lo ~2^-18 -> abs error ~1e-4, well inside tolerance.
//   - Weight fragments in REGISTERS (loop-invariant): 8 short8 = 32 VGPR.
//   - Block = 4 waves = one 16-row tile (150000 = 16*9375 exact, no tail).
//     Wave w owns col-quarter [w*16, w*16+16). Rows staged once in LDS
//     (stride 65 -> <=2-way alias, free).
//   - Fragment k-map: k = s*32 + (lane>>4)*8 + e for BOTH A and B; by the
//     sigma-freedom of MFMA (same k-permutation on A and B cancels), only
//     M=lane&15 (A) / N=lane&15 (B) and the verified C/D layout
//     (col=lane&15, row=(lane>>4)*4+reg, m89) must be right.
//   - Norm: per-wave 16-col partial via shfl_xor(1,2,4,8), cross-wave sum
//     via tiny LDS table, then normalized out-chunk write.
__global__ __launch_bounds__(256) void k_rowmv(
    const float* __restrict__ front, float* __restrict__ E,
    const float* __restrict__ Wf, const float* __restrict__ bfv,
    const float* __restrict__ Wb, const float* __restrict__ bbv,
    float* __restrict__ out, int chunk) {
    __shared__ float sf[16 * LSTR];
    __shared__ float sg[16 * LSTR];
    __shared__ float nrm[16][4];

    int t  = threadIdx.x;
    int r0 = blockIdx.x * 16;

    // Stage front and g = front*E rows into LDS (fully coalesced).
    {
        int row = t >> 4, km = (t & 15) * 4;
        const float* fp = front + (size_t)(r0 + row) * D + km;
        const float* ep = E     + (size_t)(r0 + row) * D + km;
        float4 a = *(const float4*)fp;
        float4 b = *(const float4*)ep;
        *(float4*)(sf + row * LSTR + km) = a;
        float4 gv;
        gv.x = a.x * b.x; gv.y = a.y * b.y; gv.z = a.z * b.z; gv.w = a.w * b.w;
        *(float4*)(sg + row * LSTR + km) = gv;
    }

    int lane = t & 63;
    int w    = t >> 6;          // wave id = col-quarter
    int cl   = lane & 15;       // A-row / B-col / D-col
    int kg   = lane >> 4;       // k-group

    int col = w * 16 + cl;

    // Weight fragments (hi/lo), k = s*32 + kg*8 + e. One-time, L1/L2-cached.
    short8 wfh0, wfl0, wbh0, wbl0, wfh1, wfl1, wbh1, wbl1;
    split8(Wf + (size_t)col * D +  0 + kg * 8, wfh0, wfl0);
    split8(Wb + (size_t)col * D +  0 + kg * 8, wbh0, wbl0);
    split8(Wf + (size_t)col * D + 32 + kg * 8, wfh1, wfl1);
    split8(Wb + (size_t)col * D + 32 + kg * 8, wbh1, wbl1);
    float bF = bfv[col], bB = bbv[col];

    __syncthreads();

    f32x4 accF = {0.f, 0.f, 0.f, 0.f};
    f32x4 accB = {0.f, 0.f, 0.f, 0.f};
    {
        short8 fh, fl, gh, gl;
        // kstep 0
        split8(sf + cl * LSTR +  0 + kg * 8, fh, fl);
        split8(sg + cl * LSTR +  0 + kg * 8, gh, gl);
        accF = __builtin_amdgcn_mfma_f32_16x16x32_bf16(fh, wfh0, accF, 0, 0, 0);
        accB = __builtin_amdgcn_mfma_f32_16x16x32_bf16(gh, wbh0, accB, 0, 0, 0);
        accF = __builtin_amdgcn_mfma_f32_16x16x32_bf16(fl, wfh0, accF, 0, 0, 0);
        accB = __builtin_amdgcn_mfma_f32_16x16x32_bf16(gl, wbh0, accB, 0, 0, 0);
        accF = __builtin_amdgcn_mfma_f32_16x16x32_bf16(fh, wfl0, accF, 0, 0, 0);
        accB = __builtin_amdgcn_mfma_f32_16x16x32_bf16(gh, wbl0, accB, 0, 0, 0);
        // kstep 1
        split8(sf + cl * LSTR + 32 + kg * 8, fh, fl);
        split8(sg + cl * LSTR + 32 + kg * 8, gh, gl);
        accF = __builtin_amdgcn_mfma_f32_16x16x32_bf16(fh, wfh1, accF, 0, 0, 0);
        accB = __builtin_amdgcn_mfma_f32_16x16x32_bf16(gh, wbh1, accB, 0, 0, 0);
        accF = __builtin_amdgcn_mfma_f32_16x16x32_bf16(fl, wfh1, accF, 0, 0, 0);
        accB = __builtin_amdgcn_mfma_f32_16x16x32_bf16(gl, wbh1, accB, 0, 0, 0);
        accF = __builtin_amdgcn_mfma_f32_16x16x32_bf16(fh, wfl1, accF, 0, 0, 0);
        accB = __builtin_amdgcn_mfma_f32_16x16x32_bf16(gh, wbl1, accB, 0, 0, 0);
    }

    // Epilogue: bias + lrelu + sum, per-row norm across all 64 cols.
    float e4[4], p4[4];
    #pragma unroll
    for (int rg = 0; rg < 4; rg++) {
        float aF = accF[rg] + bF;
        float aB = accB[rg] + bB;
        float vF = (aF > 0.f) ? aF : NEG * aF;
        float vB = (aB > 0.f) ? aB : NEG * aB;
        float e = vF + vB;
        e4[rg] = e;
        float p = e * e;
        p += __shfl_xor(p, 1, 64);
        p += __shfl_xor(p, 2, 64);
        p += __shfl_xor(p, 4, 64);
        p += __shfl_xor(p, 8, 64);   // sum over this wave's 16 cols
        p4[rg] = p;
    }
    if (cl == 0) {
        #pragma unroll
        for (int rg = 0; rg < 4; rg++) nrm[kg * 4 + rg][w] = p4[rg];
    }
    __syncthreads();
    #pragma unroll
    for (int rg = 0; rg < 4; rg++) {
        int row = kg * 4 + rg;
        float4 nv = *(const float4*)&nrm[row][0];
        float nsq = (nv.x + nv.y) + (nv.z + nv.w);
        float inv = 1.0f / fmaxf(sqrtf(nsq), 1e-12f);
        E[(size_t)(r0 + row) * D + col] = e4[rg];
        out[(size_t)(r0 + row) * OUTD + (size_t)chunk * D + col] = e4[rg] * inv;
    }
}

extern "C" void kernel_launch(void* const* d_in, const int* in_sizes, int n_in,
                              void* d_out, int out_size, void* d_ws, size_t ws_size,
                              hipStream_t stream) {
    const float* ue   = (const float*)d_in[0];
    const float* ie   = (const float*)d_in[1];
    const int*   erow = (const int*)d_in[2];
    const int*   ecol = (const int*)d_in[3];
    const float* eval = (const float*)d_in[4];
    const float* Wf   = (const float*)d_in[5];
    const float* bfv  = (const float*)d_in[6];
    const float* Wb   = (const float*)d_in[7];
    const float* bbv  = (const float*)d_in[8];
    float* out = (float*)d_out;

    float* E     = (float*)d_ws;                    // NTOT*D
    float* front = E + (size_t)NTOT * D;            // NTOT*D
    float* invn  = front + (size_t)NTOT * D;        // NTOT (unused, layout keep)
    int*   cnt   = (int*)(invn + NTOT);             // NTOT
    int*   offs  = cnt + NTOT;                      // NTOT+1
    int*   cur   = offs + NTOT + 1;                 // NTOT
    int*   part  = cur + NTOT;                      // 1024
    int2*  ce    = (int2*)(part + 1024);            // NEDGE int2 (col,val)

    hipMemsetAsync(cnt, 0, NTOT * sizeof(int), stream);
    k_init<<<(NTOT * 16 + 255) / 256, 256, 0, stream>>>(ue, ie, E, out);
    k_hist<<<(NEDGE + 255) / 256, 256, 0, stream>>>(erow, cnt);
    k_scan_a<<<NBLK, 256, 0, stream>>>(cnt, part);
    k_scan_b<<<1, 1024, 0, stream>>>(part);
    k_scan_c<<<NBLK, 256, 0, stream>>>(cnt, part, offs, cur);
    k_scatter<<<(NEDGE + 255) / 256, 256, 0, stream>>>(erow, ecol, eval, cur, ce);

    for (int i = 0; i < 3; i++) {
        k_spmm<<<(NTOT + 3) / 4, 256, 0, stream>>>(E, offs, ce, front);
        k_rowmv<<<NTOT / 16, 256, 0, stream>>>(
            front, E, Wf + (size_t)i * D * D, bfv + (size_t)i * D,
            Wb + (size_t)i * D * D, bbv + (size_t)i * D, out, i + 1);
    }
}